// Round 23
// baseline (100.241 us; speedup 1.0000x reference)
//
#include <hip/hip_runtime.h>
#include <hip/hip_bf16.h>

// Problem constants
#define B_  16
#define C_  6
#define T_  512
#define S_  8

#define AS1 __attribute__((address_space(1)))
#define AS3 __attribute__((address_space(3)))

typedef __attribute__((ext_vector_type(8))) short bf16x8;
typedef __attribute__((ext_vector_type(4))) float f32x4;

__device__ __forceinline__ ushort f2bf(float f) {
    __hip_bfloat16 h = __float2bfloat16(f);
    return *reinterpret_cast<ushort*>(&h);
}
__device__ __forceinline__ float bfu2f(ushort u) {
    uint x = (uint)u << 16;
    union { uint u; float f; } c; c.u = x; return c.f;
}

// ---------------------------------------------------------------------------
// Fused fp32->bf16 conversion: 4 weight matrices (512x512) + key/value (128x512).
__global__ void convert_all(const float* __restrict__ Wq, const float* __restrict__ Wo,
                            const float* __restrict__ Wk, const float* __restrict__ Wv,
                            const float* __restrict__ key, const float* __restrict__ value,
                            ushort* __restrict__ dWq, ushort* __restrict__ dWo,
                            ushort* __restrict__ dWk, ushort* __restrict__ dWv,
                            ushort* __restrict__ dkey, ushort* __restrict__ dval) {
    int y = blockIdx.y;
    int i = (blockIdx.x * 256 + threadIdx.x) * 4;
    if (y < 4) {
        const float* s = (y == 0) ? Wq : (y == 1) ? Wo : (y == 2) ? Wk : Wv;
        ushort* d = (y == 0) ? dWq : (y == 1) ? dWo : (y == 2) ? dWk : dWv;
        float4 v = *(const float4*)(s + i);
        ushort4 o;
        o.x = f2bf(v.x); o.y = f2bf(v.y); o.z = f2bf(v.z); o.w = f2bf(v.w);
        *(ushort4*)(d + i) = o;
    } else if (i < 65536) {     // 128 x 512
        float4 v = *(const float4*)(key + i);
        ushort4 o;
        o.x = f2bf(v.x); o.y = f2bf(v.y); o.z = f2bf(v.z); o.w = f2bf(v.w);
        *(ushort4*)(dkey + i) = o;
        float4 v2 = *(const float4*)(value + i);
        ushort4 o2;
        o2.x = f2bf(v2.x); o2.y = f2bf(v2.y); o2.z = f2bf(v2.z); o2.w = f2bf(v2.w);
        *(ushort4*)(dval + i) = o2;
    }
}

// ---------------------------------------------------------------------------
// K/V projections via MFMA: 8 blocks = (kv 0..1) x (bn 0..3). M=128, K=512.
__global__ __launch_bounds__(256, 2) void kvgemm(const ushort* __restrict__ keybf,
                                                 const ushort* __restrict__ valbf,
                                                 const ushort* __restrict__ Wkbf,
                                                 const ushort* __restrict__ Wvbf,
                                                 const float* __restrict__ bk,
                                                 const float* __restrict__ bv,
                                                 float* __restrict__ kout,
                                                 float* __restrict__ vout) {
    __shared__ __align__(16) ushort lds[32768];

    const int kv = blockIdx.x >> 2;
    const int bn = (blockIdx.x & 3) * 128;
    const ushort* Ain = kv ? valbf : keybf;
    const ushort* Wbf = kv ? Wvbf : Wkbf;
    const float* bias = kv ? bv : bk;
    float* out = kv ? vout : kout;

    const int tid  = threadIdx.x;
    const int lane = tid & 63;
    const int wv   = tid >> 6;
    const int wm   = (wv >> 1) * 64;
    const int wn   = (wv & 1) * 64;
    const int ln15 = lane & 15;
    const int ln16 = lane >> 4;

    auto GLDS = [&](const ushort* gbase, int rowbase, ushort* ldsbase, int k0) {
        int rb = wv * 32 + (lane >> 3);
        int c  = lane & 7;
#pragma unroll
        for (int i = 0; i < 4; ++i) {
            int r = rb + i * 8;
            const ushort* src = gbase + (long)(rowbase + r) * 512 + k0 + ((c ^ (r & 7)) << 3);
            ushort* dst = ldsbase + wv * 2048 + i * 512;
            __builtin_amdgcn_global_load_lds((AS1 const void*)src, (AS3 void*)dst, 16, 0, 0);
        }
    };

    ushort* asb0 = lds;
    ushort* asb1 = lds + 8192;
    ushort* wsb[2] = { lds + 16384, lds + 24576 };

    f32x4 acc[4][4] = {};

    auto MFMA_PHASE = [&](ushort* Asb, ushort* Wsb) {
        __builtin_amdgcn_s_setprio(1);
#pragma unroll
        for (int kj = 0; kj < 2; ++kj) {
            bf16x8 af[4], bfv[4];
#pragma unroll
            for (int mi = 0; mi < 4; ++mi) {
                int row = wm + mi * 16 + ln15;
                int ch  = kj * 4 + ln16;
                af[mi] = *(const bf16x8*)&Asb[row * 64 + ((ch ^ (row & 7)) << 3)];
            }
#pragma unroll
            for (int ni = 0; ni < 4; ++ni) {
                int row = wn + ni * 16 + ln15;
                int ch  = kj * 4 + ln16;
                bfv[ni] = *(const bf16x8*)&Wsb[row * 64 + ((ch ^ (row & 7)) << 3)];
            }
#pragma unroll
            for (int mi = 0; mi < 4; ++mi)
#pragma unroll
                for (int ni = 0; ni < 4; ++ni)
                    acc[mi][ni] = __builtin_amdgcn_mfma_f32_16x16x32_bf16(
                        af[mi], bfv[ni], acc[mi][ni], 0, 0, 0);
        }
        __builtin_amdgcn_s_setprio(0);
    };

    GLDS(Ain, 0, asb0, 0);
    GLDS(Wbf, bn, wsb[0], 0);
    asm volatile("s_waitcnt vmcnt(0) lgkmcnt(0)" ::: "memory");
    __builtin_amdgcn_sched_barrier(0);
    __builtin_amdgcn_s_barrier();
    asm volatile("" ::: "memory");
#pragma unroll
    for (int kt = 0; kt < 8; ++kt) {
        ushort* Asb = (kt & 1) ? asb1 : asb0;
        ushort* nAs = (kt & 1) ? asb0 : asb1;
        if (kt < 7) {
            GLDS(Wbf, bn, wsb[(kt + 1) & 1], (kt + 1) * 64);
            GLDS(Ain, 0, nAs, (kt + 1) * 64);
        }
        __builtin_amdgcn_sched_barrier(0);
        MFMA_PHASE(Asb, wsb[kt & 1]);
        asm volatile("s_waitcnt vmcnt(0) lgkmcnt(0)" ::: "memory");
        __builtin_amdgcn_sched_barrier(0);
        __builtin_amdgcn_s_barrier();
        asm volatile("" ::: "memory");
    }

    float bsv[4];
#pragma unroll
    for (int ni = 0; ni < 4; ++ni)
        bsv[ni] = bias[bn + wn + ni * 16 + ln15];

    float* ef = (float*)lds;
#pragma unroll
    for (int half = 0; half < 2; ++half) {
        if (wm == half * 64) {
#pragma unroll
            for (int mi = 0; mi < 4; ++mi)
#pragma unroll
                for (int j = 0; j < 4; ++j) {
                    int lr = mi * 16 + ln16 * 4 + j;
#pragma unroll
                    for (int ni = 0; ni < 4; ++ni) {
                        int col = wn + ni * 16 + ln15;
                        int cs  = col ^ ((lr & 12) << 2);
                        ef[lr * 128 + cs] = acc[mi][ni][j] + bsv[ni];
                    }
                }
        }
        asm volatile("s_waitcnt lgkmcnt(0)" ::: "memory");
        __builtin_amdgcn_sched_barrier(0);
        __builtin_amdgcn_s_barrier();
        asm volatile("" ::: "memory");
#pragma unroll
        for (int i = 0; i < 8; ++i) {
            int idx = i * 1024 + tid * 4;
            int lr = idx >> 7, col = idx & 127;
            int cs = col ^ ((lr & 12) << 2);
            float4 v = *(const float4*)&ef[lr * 128 + cs];
            *(float4*)(out + (long)(half * 64 + lr) * 512 + bn + col) = v;
        }
        if (half == 0) {
            asm volatile("" ::: "memory");
            __builtin_amdgcn_s_barrier();
            asm volatile("" ::: "memory");
        }
    }
}

// ---------------------------------------------------------------------------
// MEGA-FUSED v11: R21's v9, but grid = 256 (ONE round, 1 block/CU) with TWO
// sequential 16-row t-tiles per block. Minimal cross-tile overlap: only
// tile-B's quarter-0 loads (ra0, 24 VGPR) are issued before tile-A's
// attention phases and held across them (240 <= 256 unified budget at
// explicit launch_bounds(512,2) -- R20's spill came from the default-bounds
// 128 budget). Tile-B runs the same distance-2 schedule with q0 pre-staged;
// its prologue HBM latency hides under tile-A's attention VALU work.
__global__ __launch_bounds__(512, 2) void qattn(const float* __restrict__ query,
                                                const ushort* __restrict__ Wqbf,
                                                const float* __restrict__ bq,
                                                const float* __restrict__ kproj,
                                                const float* __restrict__ vproj,
                                                const int* __restrict__ mask,
                                                ushort* __restrict__ xout) {
    __shared__ __align__(16) ushort Abf[2][96 * 128];   // 2 x 24 KB bf16 quarters
    __shared__ int mlds[256];                           // masks for both tiles

    const int b    = blockIdx.x >> 4;
    const int tpb  = (blockIdx.x & 15) << 5;   // pair base t
    const int tid  = threadIdx.x;
    const int h    = tid >> 6;          // wave = head
    const int lane = tid & 63;
    const int ln15 = lane & 15;
    const int ln16 = lane >> 4;
    const int nb   = h * 64;

    float4 ra0[6], ra1[6];   // distance-2 staging (static alternation)
    f32x4 acc[6][4];
    uint4 br[3][4];          // distance-3 W ring (L2-resident Wq)

    auto LOADQ = [&](float4 (&ra)[6], int t0, int q) {
#pragma unroll
        for (int i = 0; i < 6; ++i) {
            int idx = i * 2048 + tid * 4;       // 0..12287 floats
            int row = idx >> 7;                 // 0..95 = c*16 + tt
            int col = idx & 127;
            int c = row >> 4, tt = row & 15;
            ra[i] = *(const float4*)(query + ((long)(b * 6 + c) * 512 + t0 + tt) * 512
                                     + q * 128 + col);
        }
    };
    auto WRITEQ = [&](float4 (&ra)[6], ushort* buf) {
#pragma unroll
        for (int i = 0; i < 6; ++i) {
            int idx = i * 2048 + tid * 4;
            int row = idx >> 7;
            int col = idx & 127;
            int kc8  = col >> 3;
            int half = (col >> 2) & 1;
            int s = (kc8 & 8) | ((kc8 & 7) ^ (row & 7));
            ushort4 p;
            p.x = f2bf(ra[i].x); p.y = f2bf(ra[i].y);
            p.z = f2bf(ra[i].z); p.w = f2bf(ra[i].w);
            *(ushort4*)((char*)buf + row * 256 + s * 16 + half * 8) = p;
        }
    };
    auto RINGINIT = [&]() {
#pragma unroll
        for (int kb = 0; kb < 3; ++kb)
#pragma unroll
            for (int nf = 0; nf < 4; ++nf)
                br[kb][nf] = *(const uint4*)(Wqbf + (long)(nb + nf * 16 + ln15) * 512
                                             + kb * 32 + ln16 * 8);
    };

#define GEMMQ(BUF, Q)                                                          \
    {                                                                          \
        const ushort* buf_ = (BUF);                                            \
        __builtin_amdgcn_s_setprio(1);                                         \
        _Pragma("unroll")                                                      \
        for (int kb8 = 0; kb8 < 4; ++kb8) {                                    \
            int kb = (Q) * 4 + kb8;                                            \
            bf16x8 af[6];                                                      \
            _Pragma("unroll")                                                  \
            for (int mf = 0; mf < 6; ++mf) {                                   \
                int row = mf * 16 + ln15;                                      \
                int kc8 = kb8 * 4 + ln16;                                      \
                int s = (kc8 & 8) | ((kc8 & 7) ^ (row & 7));                   \
                af[mf] = *(const bf16x8*)((const char*)buf_ + row * 256 + s * 16); \
            }                                                                  \
            _Pragma("unroll")                                                  \
            for (int mf = 0; mf < 6; ++mf)                                     \
                _Pragma("unroll")                                              \
                for (int nf = 0; nf < 4; ++nf)                                 \
                    acc[mf][nf] = __builtin_amdgcn_mfma_f32_16x16x32_bf16(     \
                        af[mf], *(const bf16x8*)&br[kb % 3][nf], acc[mf][nf], 0, 0, 0); \
            if (kb < 13) {                                                     \
                _Pragma("unroll")                                              \
                for (int nf = 0; nf < 4; ++nf)                                 \
                    br[(kb + 3) % 3][nf] = *(const uint4*)(Wqbf +              \
                        (long)(nb + nf * 16 + ln15) * 512 + (kb + 3) * 32 + ln16 * 8); \
            }                                                                  \
        }                                                                      \
        __builtin_amdgcn_s_setprio(0);                                         \
    }

    auto PHASES = [&](int t0, int mloff) {
        {
            float bqv[4];
#pragma unroll
            for (int nf = 0; nf < 4; ++nf) bqv[nf] = bq[nb + nf * 16 + ln15];
#pragma unroll
            for (int mf = 0; mf < 6; ++mf)
#pragma unroll
                for (int nf = 0; nf < 4; ++nf)
#pragma unroll
                    for (int j = 0; j < 4; ++j) acc[mf][nf][j] += bqv[nf];
        }
        // Phase 3: q1 = mean over c
        f32x4 q1f[4];
#pragma unroll
        for (int nf = 0; nf < 4; ++nf) {
            f32x4 s = acc[0][nf];
#pragma unroll
            for (int c = 1; c < 6; ++c) s += acc[c][nf];
            q1f[nf] = s * (1.0f / 6.0f);
        }
        // Phase 4: stage-1 attention
        float sc[4][8];
#pragma unroll
        for (int s = 0; s < 8; ++s) {
            float kv[4];
#pragma unroll
            for (int nf = 0; nf < 4; ++nf)
                kv[nf] = kproj[(long)(b * 8 + s) * 512 + nb + nf * 16 + ln15];
#pragma unroll
            for (int j = 0; j < 4; ++j) {
                float p = q1f[0][j] * kv[0] + q1f[1][j] * kv[1]
                        + q1f[2][j] * kv[2] + q1f[3][j] * kv[3];
                p += __shfl_xor(p, 1); p += __shfl_xor(p, 2);
                p += __shfl_xor(p, 4); p += __shfl_xor(p, 8);
                sc[j][s] = p * 0.125f;
            }
        }
#pragma unroll
        for (int j = 0; j < 4; ++j) {
            int tt = ln16 * 4 + j;
            int mk[8];
            float mx = -1e30f;
#pragma unroll
            for (int s = 0; s < 8; ++s) {
                mk[s] = mlds[mloff + tt * 8 + s];
                if (mk[s] == 0) sc[j][s] = -1e30f;
                mx = fmaxf(mx, sc[j][s]);
            }
            float sum = 0.f;
#pragma unroll
            for (int s = 0; s < 8; ++s) {
                float e = __expf(sc[j][s] - mx);
                sc[j][s] = e;
                sum += e;
            }
            float inv = 1.0f / sum;
#pragma unroll
            for (int s = 0; s < 8; ++s) sc[j][s] = mk[s] ? sc[j][s] * inv : 0.f;
        }
        f32x4 pcf[4] = {};
#pragma unroll
        for (int s = 0; s < 8; ++s) {
            float vv[4];
#pragma unroll
            for (int nf = 0; nf < 4; ++nf)
                vv[nf] = vproj[(long)(b * 8 + s) * 512 + nb + nf * 16 + ln15];
#pragma unroll
            for (int nf = 0; nf < 4; ++nf)
#pragma unroll
                for (int j = 0; j < 4; ++j) pcf[nf][j] += sc[j][s] * vv[nf];
        }
        // Phase 5: ss + softmax over c
        float a2[4][6];
#pragma unroll
        for (int c = 0; c < 6; ++c)
#pragma unroll
            for (int j = 0; j < 4; ++j) {
                float p = pcf[0][j] * acc[c][0][j] + pcf[1][j] * acc[c][1][j]
                        + pcf[2][j] * acc[c][2][j] + pcf[3][j] * acc[c][3][j];
                p += __shfl_xor(p, 1); p += __shfl_xor(p, 2);
                p += __shfl_xor(p, 4); p += __shfl_xor(p, 8);
                a2[j][c] = p * 0.125f;
            }
#pragma unroll
        for (int j = 0; j < 4; ++j) {
            float mx = -1e30f;
#pragma unroll
            for (int c = 0; c < 6; ++c) mx = fmaxf(mx, a2[j][c]);
            float sum = 0.f;
#pragma unroll
            for (int c = 0; c < 6; ++c) {
                float e = __expf(a2[j][c] - mx);
                a2[j][c] = e;
                sum += e;
            }
            float inv = 1.0f / sum;
#pragma unroll
            for (int c = 0; c < 6; ++c) a2[j][c] *= inv;
        }
        // Phase 6: x -> xstage (Abf[1] tail 16KB is free: last GEMM read Abf[1]
        // but all reads complete before this store after the final quarter;
        // use Abf[0] like R21 — the final GEMM read Abf[1], so Abf[0] is dead.)
        ushort* xstage = Abf[0];
#pragma unroll
        for (int nf = 0; nf < 4; ++nf)
#pragma unroll
            for (int j = 0; j < 4; ++j) {
                float x = 0.f;
#pragma unroll
                for (int c = 0; c < 6; ++c) x += a2[j][c] * acc[c][nf][j];
                xstage[(ln16 * 4 + j) * 512 + nb + nf * 16 + ln15] = f2bf(x);
            }
        __syncthreads();
        {
            int idx = tid * 16;
            int row = idx >> 9;
            int off = idx & 511;
            uint4 v0 = *(const uint4*)&xstage[row * 512 + off];
            uint4 v1 = *(const uint4*)&xstage[row * 512 + off + 8];
            ushort* dst = xout + ((long)(b * 512 + t0 + row)) * 512 + off;
            *(uint4*)dst = v0;
            *(uint4*)(dst + 8) = v1;
        }
    };

    const int t0a = tpb;
    const int t0b = tpb + 16;

    if (tid < 256) mlds[tid] = mask[((long)b * 512 + tpb + (tid >> 3)) * 8 + (tid & 7)];

    // ================= TILE A (R21 schedule) =================
    LOADQ(ra0, t0a, 0);
    WRITEQ(ra0, Abf[0]);
    LOADQ(ra1, t0a, 1);
    __builtin_amdgcn_sched_barrier(0);
    __syncthreads();

#pragma unroll
    for (int mf = 0; mf < 6; ++mf)
#pragma unroll
        for (int nf = 0; nf < 4; ++nf) acc[mf][nf] = (f32x4){0.f, 0.f, 0.f, 0.f};
    RINGINIT();

    LOADQ(ra0, t0a, 2);
    __builtin_amdgcn_sched_barrier(0);
    GEMMQ(Abf[0], 0);
    WRITEQ(ra1, Abf[1]);
    __syncthreads();

    LOADQ(ra1, t0a, 3);
    __builtin_amdgcn_sched_barrier(0);
    GEMMQ(Abf[1], 1);
    WRITEQ(ra0, Abf[0]);
    __syncthreads();

    GEMMQ(Abf[0], 2);
    WRITEQ(ra1, Abf[1]);
    __syncthreads();

    GEMMQ(Abf[1], 3);

    // issue tile-B q0 loads; they fly under tile-A's attention phases
    LOADQ(ra0, t0b, 0);
    __builtin_amdgcn_sched_barrier(0);

    PHASES(t0a, 0);
    __syncthreads();            // xstage reads complete before reuse

    // ================= TILE B =================
    WRITEQ(ra0, Abf[0]);        // q0 (loads landed during PHASES)
    LOADQ(ra1, t0b, 1);
    __builtin_amdgcn_sched_barrier(0);
    __syncthreads();

#pragma unroll
    for (int mf = 0; mf < 6; ++mf)
#pragma unroll
        for (int nf = 0; nf < 4; ++nf) acc[mf][nf] = (f32x4){0.f, 0.f, 0.f, 0.f};
    RINGINIT();

    LOADQ(ra0, t0b, 2);
    __builtin_amdgcn_sched_barrier(0);
    GEMMQ(Abf[0], 0);
    WRITEQ(ra1, Abf[1]);
    __syncthreads();

    LOADQ(ra1, t0b, 3);
    __builtin_amdgcn_sched_barrier(0);
    GEMMQ(Abf[1], 1);
    WRITEQ(ra0, Abf[0]);
    __syncthreads();

    GEMMQ(Abf[0], 2);
    WRITEQ(ra1, Abf[1]);
    __syncthreads();

    GEMMQ(Abf[1], 3);

    PHASES(t0b, 128);
#undef GEMMQ
}

// ---------------------------------------------------------------------------
// MFMA bf16 GEMM (R9 structure) — output projection only.
__global__ __launch_bounds__(256, 2)
void gemm_mfma(const void* __restrict__ Ain,
               const ushort* __restrict__ Wbf,
               const float* __restrict__ bias,
               void* __restrict__ out, int mpanels) {
    __shared__ __align__(16) ushort lds[32768];

    const int bid = blockIdx.x;
    const int cpx = (mpanels * 4) >> 3;
    const int swz = (bid & 7) * cpx + (bid >> 3);
    const int bm = (swz >> 2) * 128;
    const int bn = (swz & 3) * 128;

    const int tid  = threadIdx.x;
    const int lane = tid & 63;
    const int wv   = tid >> 6;
    const int wm   = (wv >> 1) * 64;
    const int wn   = (wv & 1) * 64;
    const int ln15 = lane & 15;
    const int ln16 = lane >> 4;

    auto GLDS = [&](const ushort* gbase, int rowbase, ushort* ldsbase, int k0) {
        int rb = wv * 32 + (lane >> 3);
        int c  = lane & 7;
#pragma unroll
        for (int i = 0; i < 4; ++i) {
            int r = rb + i * 8;
            const ushort* src = gbase + (long)(rowbase + r) * 512 + k0 + ((c ^ (r & 7)) << 3);
            ushort* dst = ldsbase + wv * 2048 + i * 512;
            __builtin_amdgcn_global_load_lds((AS1 const void*)src, (AS3 void*)dst, 16, 0, 0);
        }
    };

    ushort* asb0 = lds;
    ushort* asb1 = lds + 8192;
    ushort* wsb[2] = { lds + 16384, lds + 24576 };

    f32x4 acc[4][4] = {};

    auto MFMA_PHASE = [&](ushort* Asb, ushort* Wsb) {
        __builtin_amdgcn_s_setprio(1);
#pragma unroll
        for (int kj = 0; kj < 2; ++kj) {
            bf16x8 af[4], bfv[4];
#pragma unroll
            for (int mi = 0; mi < 4; ++mi) {
                int row = wm + mi * 16 + ln15;
                int ch  = kj * 4 + ln16;
                af[mi] = *(const bf16x8*)&Asb[row * 64 + ((ch ^ (row & 7)) << 3)];
            }
#pragma unroll
            for (int ni = 0; ni < 4; ++ni) {
                int row = wn + ni * 16 + ln15;
                int ch  = kj * 4 + ln16;
                bfv[ni] = *(const bf16x8*)&Wsb[row * 64 + ((ch ^ (row & 7)) << 3)];
            }
#pragma unroll
            for (int mi = 0; mi < 4; ++mi)
#pragma unroll
                for (int ni = 0; ni < 4; ++ni)
                    acc[mi][ni] = __builtin_amdgcn_mfma_f32_16x16x32_bf16(
                        af[mi], bfv[ni], acc[mi][ni], 0, 0, 0);
        }
        __builtin_amdgcn_s_setprio(0);
    };

    GLDS((const ushort*)Ain, bm, asb0, 0);
    GLDS(Wbf, bn, wsb[0], 0);
    asm volatile("s_waitcnt vmcnt(0) lgkmcnt(0)" ::: "memory");
    __builtin_amdgcn_sched_barrier(0);
    __builtin_amdgcn_s_barrier();
    asm volatile("" ::: "memory");
#pragma unroll
    for (int kt = 0; kt < 8; ++kt) {
        ushort* Asb = (kt & 1) ? asb1 : asb0;
        ushort* nAs = (kt & 1) ? asb0 : asb1;
        if (kt < 7) {
            GLDS(Wbf, bn, wsb[(kt + 1) & 1], (kt + 1) * 64);
            GLDS((const ushort*)Ain, bm, nAs, (kt + 1) * 64);
        }
        __builtin_amdgcn_sched_barrier(0);
        MFMA_PHASE(Asb, wsb[kt & 1]);
        asm volatile("s_waitcnt vmcnt(0) lgkmcnt(0)" ::: "memory");
        __builtin_amdgcn_sched_barrier(0);
        __builtin_amdgcn_s_barrier();
        asm volatile("" ::: "memory");
    }

    float bsv[4];
#pragma unroll
    for (int ni = 0; ni < 4; ++ni)
        bsv[ni] = bias[bn + wn + ni * 16 + ln15];

    float* ef = (float*)lds;
#pragma unroll
    for (int half = 0; half < 2; ++half) {
        if (wm == half * 64) {
#pragma unroll
            for (int mi = 0; mi < 4; ++mi)
#pragma unroll
                for (int j = 0; j < 4; ++j) {
                    int lr = mi * 16 + ln16 * 4 + j;
#pragma unroll
                    for (int ni = 0; ni < 4; ++ni) {
                        int col = wn + ni * 16 + ln15;
                        int cs  = col ^ ((lr & 12) << 2);
                        ef[lr * 128 + cs] = acc[mi][ni][j] + bsv[ni];
                    }
                }
        }
        asm volatile("s_waitcnt lgkmcnt(0)" ::: "memory");
        __builtin_amdgcn_sched_barrier(0);
        __builtin_amdgcn_s_barrier();
        asm volatile("" ::: "memory");
#pragma unroll
        for (int i = 0; i < 8; ++i) {
            int idx = i * 1024 + tid * 4;
            int lr = idx >> 7, col = idx & 127;
            int cs = col ^ ((lr & 12) << 2);
            float4 v = *(const float4*)&ef[lr * 128 + cs];
            *(float4*)((float*)out + (long)(bm + half * 64 + lr) * 512 + bn + col) = v;
        }
        if (half == 0) {
            asm volatile("" ::: "memory");
            __builtin_amdgcn_s_barrier();
            asm volatile("" ::: "memory");
        }
    }
}

// ---------------------------------------------------------------------------
extern "C" void kernel_launch(void* const* d_in, const int* in_sizes, int n_in,
                              void* d_out, int out_size, void* d_ws, size_t ws_size,
                              hipStream_t stream) {
    const float* query = (const float*)d_in[0];
    const float* key   = (const float*)d_in[1];
    const float* value = (const float*)d_in[2];
    const int*   mask  = (const int*)d_in[3];
    const float* Wq = (const float*)d_in[4];
    const float* bq = (const float*)d_in[5];
    const float* Wk = (const float*)d_in[6];
    const float* bk = (const float*)d_in[7];
    const float* Wv = (const float*)d_in[8];
    const float* bv = (const float*)d_in[9];
    const float* Wo = (const float*)d_in[10];
    const float* bo = (const float*)d_in[11];
    float* out = (float*)d_out;

    char* ws = (char*)d_ws;
    ushort* Wqbf  = (ushort*)(ws + 0);                  // 512 KB
    ushort* Wobf  = (ushort*)(ws + 524288u);            // 512 KB
    ushort* Wkbf  = (ushort*)(ws + 1048576u);           // 512 KB
    ushort* Wvbf  = (ushort*)(ws + 1572864u);           // 512 KB
    ushort* keybf = (ushort*)(ws + 2097152u);           // 128 KB
    ushort* valbf = (ushort*)(ws + 2228224u);           // 128 KB
    float*  kproj = (float*)(ws + 2621440u);            // 256 KB
    float*  vproj = (float*)(ws + 2883584u);            // 256 KB
    ushort* xbf   = (ushort*)(ws + (4u << 20));         // 8 MB (8192 x 512 bf16)

    // fp32->bf16: 4 weights + key/value, one dispatch
    convert_all<<<dim3(256, 5), 256, 0, stream>>>(Wq, Wo, Wk, Wv, key, value,
                                                  Wqbf, Wobf, Wkbf, Wvbf, keybf, valbf);

    // K/V projections via MFMA: 8 blocks
    kvgemm<<<8, 256, 0, stream>>>(keybf, valbf, Wkbf, Wvbf, bk, bv, kproj, vproj);

    // fused q-projection + two-stage attention: 256 blocks x 2 t-tiles
    qattn<<<256, 512, 0, stream>>>(query, Wqbf, bq, kproj, vproj, mask, xbf);

    // output projection: M = 8192, bf16 A, fp32 out
    gemm_mfma<<<256, 256, 0, stream>>>(xbf, Wobf, bo, out, 64);

    (void)in_sizes; (void)n_in; (void)out_size; (void)ws_size;
}

// Round 24
// 83.392 us; speedup vs baseline: 1.2020x; 1.2020x over previous
//
#include <hip/hip_runtime.h>
#include <hip/hip_bf16.h>

// Problem constants
#define B_  16
#define C_  6
#define T_  512
#define S_  8

#define AS1 __attribute__((address_space(1)))
#define AS3 __attribute__((address_space(3)))

typedef __attribute__((ext_vector_type(8))) short bf16x8;
typedef __attribute__((ext_vector_type(4))) float f32x4;

__device__ __forceinline__ ushort f2bf(float f) {
    __hip_bfloat16 h = __float2bfloat16(f);
    return *reinterpret_cast<ushort*>(&h);
}
__device__ __forceinline__ float bfu2f(ushort u) {
    uint x = (uint)u << 16;
    union { uint u; float f; } c; c.u = x; return c.f;
}

// ---------------------------------------------------------------------------
// Fused fp32->bf16 conversion: 4 weight matrices (512x512) + key/value (128x512).
__global__ void convert_all(const float* __restrict__ Wq, const float* __restrict__ Wo,
                            const float* __restrict__ Wk, const float* __restrict__ Wv,
                            const float* __restrict__ key, const float* __restrict__ value,
                            ushort* __restrict__ dWq, ushort* __restrict__ dWo,
                            ushort* __restrict__ dWk, ushort* __restrict__ dWv,
                            ushort* __restrict__ dkey, ushort* __restrict__ dval) {
    int y = blockIdx.y;
    int i = (blockIdx.x * 256 + threadIdx.x) * 4;
    if (y < 4) {
        const float* s = (y == 0) ? Wq : (y == 1) ? Wo : (y == 2) ? Wk : Wv;
        ushort* d = (y == 0) ? dWq : (y == 1) ? dWo : (y == 2) ? dWk : dWv;
        float4 v = *(const float4*)(s + i);
        ushort4 o;
        o.x = f2bf(v.x); o.y = f2bf(v.y); o.z = f2bf(v.z); o.w = f2bf(v.w);
        *(ushort4*)(d + i) = o;
    } else if (i < 65536) {     // 128 x 512
        float4 v = *(const float4*)(key + i);
        ushort4 o;
        o.x = f2bf(v.x); o.y = f2bf(v.y); o.z = f2bf(v.z); o.w = f2bf(v.w);
        *(ushort4*)(dkey + i) = o;
        float4 v2 = *(const float4*)(value + i);
        ushort4 o2;
        o2.x = f2bf(v2.x); o2.y = f2bf(v2.y); o2.z = f2bf(v2.z); o2.w = f2bf(v2.w);
        *(ushort4*)(dval + i) = o2;
    }
}

// ---------------------------------------------------------------------------
// K/V projections via MFMA: 8 blocks = (kv 0..1) x (bn 0..3). M=128, K=512.
__global__ __launch_bounds__(256, 2) void kvgemm(const ushort* __restrict__ keybf,
                                                 const ushort* __restrict__ valbf,
                                                 const ushort* __restrict__ Wkbf,
                                                 const ushort* __restrict__ Wvbf,
                                                 const float* __restrict__ bk,
                                                 const float* __restrict__ bv,
                                                 float* __restrict__ kout,
                                                 float* __restrict__ vout) {
    __shared__ __align__(16) ushort lds[32768];

    const int kv = blockIdx.x >> 2;
    const int bn = (blockIdx.x & 3) * 128;
    const ushort* Ain = kv ? valbf : keybf;
    const ushort* Wbf = kv ? Wvbf : Wkbf;
    const float* bias = kv ? bv : bk;
    float* out = kv ? vout : kout;

    const int tid  = threadIdx.x;
    const int lane = tid & 63;
    const int wv   = tid >> 6;
    const int wm   = (wv >> 1) * 64;
    const int wn   = (wv & 1) * 64;
    const int ln15 = lane & 15;
    const int ln16 = lane >> 4;

    auto GLDS = [&](const ushort* gbase, int rowbase, ushort* ldsbase, int k0) {
        int rb = wv * 32 + (lane >> 3);
        int c  = lane & 7;
#pragma unroll
        for (int i = 0; i < 4; ++i) {
            int r = rb + i * 8;
            const ushort* src = gbase + (long)(rowbase + r) * 512 + k0 + ((c ^ (r & 7)) << 3);
            ushort* dst = ldsbase + wv * 2048 + i * 512;
            __builtin_amdgcn_global_load_lds((AS1 const void*)src, (AS3 void*)dst, 16, 0, 0);
        }
    };

    ushort* asb0 = lds;
    ushort* asb1 = lds + 8192;
    ushort* wsb[2] = { lds + 16384, lds + 24576 };

    f32x4 acc[4][4] = {};

    auto MFMA_PHASE = [&](ushort* Asb, ushort* Wsb) {
        __builtin_amdgcn_s_setprio(1);
#pragma unroll
        for (int kj = 0; kj < 2; ++kj) {
            bf16x8 af[4], bfv[4];
#pragma unroll
            for (int mi = 0; mi < 4; ++mi) {
                int row = wm + mi * 16 + ln15;
                int ch  = kj * 4 + ln16;
                af[mi] = *(const bf16x8*)&Asb[row * 64 + ((ch ^ (row & 7)) << 3)];
            }
#pragma unroll
            for (int ni = 0; ni < 4; ++ni) {
                int row = wn + ni * 16 + ln15;
                int ch  = kj * 4 + ln16;
                bfv[ni] = *(const bf16x8*)&Wsb[row * 64 + ((ch ^ (row & 7)) << 3)];
            }
#pragma unroll
            for (int mi = 0; mi < 4; ++mi)
#pragma unroll
                for (int ni = 0; ni < 4; ++ni)
                    acc[mi][ni] = __builtin_amdgcn_mfma_f32_16x16x32_bf16(
                        af[mi], bfv[ni], acc[mi][ni], 0, 0, 0);
        }
        __builtin_amdgcn_s_setprio(0);
    };

    GLDS(Ain, 0, asb0, 0);
    GLDS(Wbf, bn, wsb[0], 0);
    asm volatile("s_waitcnt vmcnt(0) lgkmcnt(0)" ::: "memory");
    __builtin_amdgcn_sched_barrier(0);
    __builtin_amdgcn_s_barrier();
    asm volatile("" ::: "memory");
#pragma unroll
    for (int kt = 0; kt < 8; ++kt) {
        ushort* Asb = (kt & 1) ? asb1 : asb0;
        ushort* nAs = (kt & 1) ? asb0 : asb1;
        if (kt < 7) {
            GLDS(Wbf, bn, wsb[(kt + 1) & 1], (kt + 1) * 64);
            GLDS(Ain, 0, nAs, (kt + 1) * 64);
        }
        __builtin_amdgcn_sched_barrier(0);
        MFMA_PHASE(Asb, wsb[kt & 1]);
        asm volatile("s_waitcnt vmcnt(0) lgkmcnt(0)" ::: "memory");
        __builtin_amdgcn_sched_barrier(0);
        __builtin_amdgcn_s_barrier();
        asm volatile("" ::: "memory");
    }

    float bsv[4];
#pragma unroll
    for (int ni = 0; ni < 4; ++ni)
        bsv[ni] = bias[bn + wn + ni * 16 + ln15];

    float* ef = (float*)lds;
#pragma unroll
    for (int half = 0; half < 2; ++half) {
        if (wm == half * 64) {
#pragma unroll
            for (int mi = 0; mi < 4; ++mi)
#pragma unroll
                for (int j = 0; j < 4; ++j) {
                    int lr = mi * 16 + ln16 * 4 + j;
#pragma unroll
                    for (int ni = 0; ni < 4; ++ni) {
                        int col = wn + ni * 16 + ln15;
                        int cs  = col ^ ((lr & 12) << 2);
                        ef[lr * 128 + cs] = acc[mi][ni][j] + bsv[ni];
                    }
                }
        }
        asm volatile("s_waitcnt lgkmcnt(0)" ::: "memory");
        __builtin_amdgcn_sched_barrier(0);
        __builtin_amdgcn_s_barrier();
        asm volatile("" ::: "memory");
#pragma unroll
        for (int i = 0; i < 8; ++i) {
            int idx = i * 1024 + tid * 4;
            int lr = idx >> 7, col = idx & 127;
            int cs = col ^ ((lr & 12) << 2);
            float4 v = *(const float4*)&ef[lr * 128 + cs];
            *(float4*)(out + (long)(half * 64 + lr) * 512 + bn + col) = v;
        }
        if (half == 0) {
            asm volatile("" ::: "memory");
            __builtin_amdgcn_s_barrier();
            asm volatile("" ::: "memory");
        }
    }
}

// ---------------------------------------------------------------------------
// MEGA-FUSED v9 (R21 best): block = 16 t-rows of one b; 512 threads = 8 waves;
// WAVE = HEAD. q stays in MFMA accumulators acc[6c][4nf]. DISTANCE-2 staging
// via two named ra sets: each WRITEQ drains loads issued ~1.5 quarters
// earlier. ra0/ra1 both dead before the attention phases (no cross-phase
// register residency -> no spill); launch_bounds(512,2) = 256-reg budget.
__global__ __launch_bounds__(512, 2) void qattn(const float* __restrict__ query,
                                                const ushort* __restrict__ Wqbf,
                                                const float* __restrict__ bq,
                                                const float* __restrict__ kproj,
                                                const float* __restrict__ vproj,
                                                const int* __restrict__ mask,
                                                ushort* __restrict__ xout) {
    __shared__ __align__(16) ushort Abf[2][96 * 128];   // 2 x 24 KB bf16 quarters
    __shared__ int mlds[128];

    const int b   = blockIdx.x >> 5;
    const int t0  = (blockIdx.x & 31) << 4;
    const int tid = threadIdx.x;
    const int h    = tid >> 6;          // wave = head
    const int lane = tid & 63;
    const int ln15 = lane & 15;
    const int ln16 = lane >> 4;
    const int nb   = h * 64;

    float4 ra0[6], ra1[6];   // distance-2 staging (static alternation)

    auto LOADQ = [&](float4 (&ra)[6], int q) {
#pragma unroll
        for (int i = 0; i < 6; ++i) {
            int idx = i * 2048 + tid * 4;       // 0..12287 floats
            int row = idx >> 7;                 // 0..95 = c*16 + tt
            int col = idx & 127;
            int c = row >> 4, tt = row & 15;
            ra[i] = *(const float4*)(query + ((long)(b * 6 + c) * 512 + t0 + tt) * 512
                                     + q * 128 + col);
        }
    };
    auto WRITEQ = [&](float4 (&ra)[6], ushort* buf) {
#pragma unroll
        for (int i = 0; i < 6; ++i) {
            int idx = i * 2048 + tid * 4;
            int row = idx >> 7;
            int col = idx & 127;
            int kc8  = col >> 3;
            int half = (col >> 2) & 1;
            int s = (kc8 & 8) | ((kc8 & 7) ^ (row & 7));
            ushort4 p;
            p.x = f2bf(ra[i].x); p.y = f2bf(ra[i].y);
            p.z = f2bf(ra[i].z); p.w = f2bf(ra[i].w);
            *(ushort4*)((char*)buf + row * 256 + s * 16 + half * 8) = p;
        }
    };

    if (tid < 128) mlds[tid] = mask[((long)b * 512 + t0 + (tid >> 3)) * 8 + (tid & 7)];

    // ---- prologue: q0 staged; q1 in flight ----
    LOADQ(ra0, 0);
    WRITEQ(ra0, Abf[0]);
    LOADQ(ra1, 1);
    __builtin_amdgcn_sched_barrier(0);
    __syncthreads();

    // ---- q-GEMM over 4 K-quarters, acc stays in AGPRs ----
    f32x4 acc[6][4] = {};
    uint4 br[3][4];                     // distance-3 W ring (L2-resident Wq)
#pragma unroll
    for (int kb = 0; kb < 3; ++kb)
#pragma unroll
        for (int nf = 0; nf < 4; ++nf)
            br[kb][nf] = *(const uint4*)(Wqbf + (long)(nb + nf * 16 + ln15) * 512
                                         + kb * 32 + ln16 * 8);

#define GEMMQ(BUF, Q)                                                          \
    {                                                                          \
        const ushort* buf_ = (BUF);                                            \
        __builtin_amdgcn_s_setprio(1);                                         \
        _Pragma("unroll")                                                      \
        for (int kb8 = 0; kb8 < 4; ++kb8) {                                    \
            int kb = (Q) * 4 + kb8;                                            \
            bf16x8 af[6];                                                      \
            _Pragma("unroll")                                                  \
            for (int mf = 0; mf < 6; ++mf) {                                   \
                int row = mf * 16 + ln15;                                      \
                int kc8 = kb8 * 4 + ln16;                                      \
                int s = (kc8 & 8) | ((kc8 & 7) ^ (row & 7));                   \
                af[mf] = *(const bf16x8*)((const char*)buf_ + row * 256 + s * 16); \
            }                                                                  \
            _Pragma("unroll")                                                  \
            for (int mf = 0; mf < 6; ++mf)                                     \
                _Pragma("unroll")                                              \
                for (int nf = 0; nf < 4; ++nf)                                 \
                    acc[mf][nf] = __builtin_amdgcn_mfma_f32_16x16x32_bf16(     \
                        af[mf], *(const bf16x8*)&br[kb % 3][nf], acc[mf][nf], 0, 0, 0); \
            if (kb < 13) {                                                     \
                _Pragma("unroll")                                              \
                for (int nf = 0; nf < 4; ++nf)                                 \
                    br[(kb + 3) % 3][nf] = *(const uint4*)(Wqbf +              \
                        (long)(nb + nf * 16 + ln15) * 512 + (kb + 3) * 32 + ln16 * 8); \
            }                                                                  \
        }                                                                      \
        __builtin_amdgcn_s_setprio(0);                                         \
    }

    // q0: issue q2 -> ra0 (free); GEMM q0; write q1 (issued in prologue)
    LOADQ(ra0, 2);
    __builtin_amdgcn_sched_barrier(0);
    GEMMQ(Abf[0], 0);
    WRITEQ(ra1, Abf[1]);
    __syncthreads();

    // q1: issue q3 -> ra1; GEMM q1; write q2 (cover: q0 tail + q1 GEMM)
    LOADQ(ra1, 3);
    __builtin_amdgcn_sched_barrier(0);
    GEMMQ(Abf[1], 1);
    WRITEQ(ra0, Abf[0]);
    __syncthreads();

    // q2: GEMM q2; write q3 (cover: q1 tail + q2 GEMM)
    GEMMQ(Abf[0], 2);
    WRITEQ(ra1, Abf[1]);
    __syncthreads();

    // q3: GEMM q3
    GEMMQ(Abf[1], 3);
#undef GEMMQ

    {
        float bqv[4];
#pragma unroll
        for (int nf = 0; nf < 4; ++nf) bqv[nf] = bq[nb + nf * 16 + ln15];
#pragma unroll
        for (int mf = 0; mf < 6; ++mf)
#pragma unroll
            for (int nf = 0; nf < 4; ++nf)
#pragma unroll
                for (int j = 0; j < 4; ++j) acc[mf][nf][j] += bqv[nf];
    }

    // ---- Phase 3: q1 = mean over c (frag-elementwise, all-local) ----
    f32x4 q1f[4];
#pragma unroll
    for (int nf = 0; nf < 4; ++nf) {
        f32x4 s = acc[0][nf];
#pragma unroll
        for (int c = 1; c < 6; ++c) s += acc[c][nf];
        q1f[nf] = s * (1.0f / 6.0f);
    }

    // ---- Phase 4: stage-1 attention (head-local) ----
    float sc[4][8];
#pragma unroll
    for (int s = 0; s < 8; ++s) {
        float kv[4];
#pragma unroll
        for (int nf = 0; nf < 4; ++nf)
            kv[nf] = kproj[(long)(b * 8 + s) * 512 + nb + nf * 16 + ln15];
#pragma unroll
        for (int j = 0; j < 4; ++j) {
            float p = q1f[0][j] * kv[0] + q1f[1][j] * kv[1]
                    + q1f[2][j] * kv[2] + q1f[3][j] * kv[3];
            p += __shfl_xor(p, 1); p += __shfl_xor(p, 2);
            p += __shfl_xor(p, 4); p += __shfl_xor(p, 8);
            sc[j][s] = p * 0.125f;
        }
    }
#pragma unroll
    for (int j = 0; j < 4; ++j) {
        int tt = ln16 * 4 + j;
        int mk[8];
        float mx = -1e30f;
#pragma unroll
        for (int s = 0; s < 8; ++s) {
            mk[s] = mlds[tt * 8 + s];
            if (mk[s] == 0) sc[j][s] = -1e30f;
            mx = fmaxf(mx, sc[j][s]);
        }
        float sum = 0.f;
#pragma unroll
        for (int s = 0; s < 8; ++s) {
            float e = __expf(sc[j][s] - mx);
            sc[j][s] = e;
            sum += e;
        }
        float inv = 1.0f / sum;
#pragma unroll
        for (int s = 0; s < 8; ++s) sc[j][s] = mk[s] ? sc[j][s] * inv : 0.f;
    }
    f32x4 pcf[4] = {};
#pragma unroll
    for (int s = 0; s < 8; ++s) {
        float vv[4];
#pragma unroll
        for (int nf = 0; nf < 4; ++nf)
            vv[nf] = vproj[(long)(b * 8 + s) * 512 + nb + nf * 16 + ln15];
#pragma unroll
        for (int nf = 0; nf < 4; ++nf)
#pragma unroll
            for (int j = 0; j < 4; ++j) pcf[nf][j] += sc[j][s] * vv[nf];
    }

    // ---- Phase 5: ss + softmax over c (all-local) ----
    float a2[4][6];
#pragma unroll
    for (int c = 0; c < 6; ++c)
#pragma unroll
        for (int j = 0; j < 4; ++j) {
            float p = pcf[0][j] * acc[c][0][j] + pcf[1][j] * acc[c][1][j]
                    + pcf[2][j] * acc[c][2][j] + pcf[3][j] * acc[c][3][j];
            p += __shfl_xor(p, 1); p += __shfl_xor(p, 2);
            p += __shfl_xor(p, 4); p += __shfl_xor(p, 8);
            a2[j][c] = p * 0.125f;
        }
#pragma unroll
    for (int j = 0; j < 4; ++j) {
        float mx = -1e30f;
#pragma unroll
        for (int c = 0; c < 6; ++c) mx = fmaxf(mx, a2[j][c]);
        float sum = 0.f;
#pragma unroll
        for (int c = 0; c < 6; ++c) {
            float e = __expf(a2[j][c] - mx);
            a2[j][c] = e;
            sum += e;
        }
        float inv = 1.0f / sum;
#pragma unroll
        for (int c = 0; c < 6; ++c) a2[j][c] *= inv;
    }

    // ---- Phase 6: x = sum_c a2_c * q_c ; stage via LDS; coalesced store ----
    ushort* xstage = Abf[0];   // 16 rows x 512 bf16 = 16 KB, Abf dead
#pragma unroll
    for (int nf = 0; nf < 4; ++nf)
#pragma unroll
        for (int j = 0; j < 4; ++j) {
            float x = 0.f;
#pragma unroll
            for (int c = 0; c < 6; ++c) x += a2[j][c] * acc[c][nf][j];
            xstage[(ln16 * 4 + j) * 512 + nb + nf * 16 + ln15] = f2bf(x);
        }
    __syncthreads();
    {
        int idx = tid * 16;
        int row = idx >> 9;
        int off = idx & 511;
        uint4 v0 = *(const uint4*)&xstage[row * 512 + off];
        uint4 v1 = *(const uint4*)&xstage[row * 512 + off + 8];
        ushort* dst = xout + ((long)(b * 512 + t0 + row)) * 512 + off;
        *(uint4*)dst = v0;
        *(uint4*)(dst + 8) = v1;
    }
}

// ---------------------------------------------------------------------------
// MFMA bf16 GEMM (R9 structure) — output projection only.
__global__ __launch_bounds__(256, 2)
void gemm_mfma(const void* __restrict__ Ain,
               const ushort* __restrict__ Wbf,
               const float* __restrict__ bias,
               void* __restrict__ out, int mpanels) {
    __shared__ __align__(16) ushort lds[32768];

    const int bid = blockIdx.x;
    const int cpx = (mpanels * 4) >> 3;
    const int swz = (bid & 7) * cpx + (bid >> 3);
    const int bm = (swz >> 2) * 128;
    const int bn = (swz & 3) * 128;

    const int tid  = threadIdx.x;
    const int lane = tid & 63;
    const int wv   = tid >> 6;
    const int wm   = (wv >> 1) * 64;
    const int wn   = (wv & 1) * 64;
    const int ln15 = lane & 15;
    const int ln16 = lane >> 4;

    auto GLDS = [&](const ushort* gbase, int rowbase, ushort* ldsbase, int k0) {
        int rb = wv * 32 + (lane >> 3);
        int c  = lane & 7;
#pragma unroll
        for (int i = 0; i < 4; ++i) {
            int r = rb + i * 8;
            const ushort* src = gbase + (long)(rowbase + r) * 512 + k0 + ((c ^ (r & 7)) << 3);
            ushort* dst = ldsbase + wv * 2048 + i * 512;
            __builtin_amdgcn_global_load_lds((AS1 const void*)src, (AS3 void*)dst, 16, 0, 0);
        }
    };

    ushort* asb0 = lds;
    ushort* asb1 = lds + 8192;
    ushort* wsb[2] = { lds + 16384, lds + 24576 };

    f32x4 acc[4][4] = {};

    auto MFMA_PHASE = [&](ushort* Asb, ushort* Wsb) {
        __builtin_amdgcn_s_setprio(1);
#pragma unroll
        for (int kj = 0; kj < 2; ++kj) {
            bf16x8 af[4], bfv[4];
#pragma unroll
            for (int mi = 0; mi < 4; ++mi) {
                int row = wm + mi * 16 + ln15;
                int ch  = kj * 4 + ln16;
                af[mi] = *(const bf16x8*)&Asb[row * 64 + ((ch ^ (row & 7)) << 3)];
            }
#pragma unroll
            for (int ni = 0; ni < 4; ++ni) {
                int row = wn + ni * 16 + ln15;
                int ch  = kj * 4 + ln16;
                bfv[ni] = *(const bf16x8*)&Wsb[row * 64 + ((ch ^ (row & 7)) << 3)];
            }
#pragma unroll
            for (int mi = 0; mi < 4; ++mi)
#pragma unroll
                for (int ni = 0; ni < 4; ++ni)
                    acc[mi][ni] = __builtin_amdgcn_mfma_f32_16x16x32_bf16(
                        af[mi], bfv[ni], acc[mi][ni], 0, 0, 0);
        }
        __builtin_amdgcn_s_setprio(0);
    };

    GLDS((const ushort*)Ain, bm, asb0, 0);
    GLDS(Wbf, bn, wsb[0], 0);
    asm volatile("s_waitcnt vmcnt(0) lgkmcnt(0)" ::: "memory");
    __builtin_amdgcn_sched_barrier(0);
    __builtin_amdgcn_s_barrier();
    asm volatile("" ::: "memory");
#pragma unroll
    for (int kt = 0; kt < 8; ++kt) {
        ushort* Asb = (kt & 1) ? asb1 : asb0;
        ushort* nAs = (kt & 1) ? asb0 : asb1;
        if (kt < 7) {
            GLDS(Wbf, bn, wsb[(kt + 1) & 1], (kt + 1) * 64);
            GLDS((const ushort*)Ain, bm, nAs, (kt + 1) * 64);
        }
        __builtin_amdgcn_sched_barrier(0);
        MFMA_PHASE(Asb, wsb[kt & 1]);
        asm volatile("s_waitcnt vmcnt(0) lgkmcnt(0)" ::: "memory");
        __builtin_amdgcn_sched_barrier(0);
        __builtin_amdgcn_s_barrier();
        asm volatile("" ::: "memory");
    }

    float bsv[4];
#pragma unroll
    for (int ni = 0; ni < 4; ++ni)
        bsv[ni] = bias[bn + wn + ni * 16 + ln15];

    float* ef = (float*)lds;
#pragma unroll
    for (int half = 0; half < 2; ++half) {
        if (wm == half * 64) {
#pragma unroll
            for (int mi = 0; mi < 4; ++mi)
#pragma unroll
                for (int j = 0; j < 4; ++j) {
                    int lr = mi * 16 + ln16 * 4 + j;
#pragma unroll
                    for (int ni = 0; ni < 4; ++ni) {
                        int col = wn + ni * 16 + ln15;
                        int cs  = col ^ ((lr & 12) << 2);
                        ef[lr * 128 + cs] = acc[mi][ni][j] + bsv[ni];
                    }
                }
        }
        asm volatile("s_waitcnt lgkmcnt(0)" ::: "memory");
        __builtin_amdgcn_sched_barrier(0);
        __builtin_amdgcn_s_barrier();
        asm volatile("" ::: "memory");
#pragma unroll
        for (int i = 0; i < 8; ++i) {
            int idx = i * 1024 + tid * 4;
            int lr = idx >> 7, col = idx & 127;
            int cs = col ^ ((lr & 12) << 2);
            float4 v = *(const float4*)&ef[lr * 128 + cs];
            *(float4*)((float*)out + (long)(bm + half * 64 + lr) * 512 + bn + col) = v;
        }
        if (half == 0) {
            asm volatile("" ::: "memory");
            __builtin_amdgcn_s_barrier();
            asm volatile("" ::: "memory");
        }
    }
}

// ---------------------------------------------------------------------------
extern "C" void kernel_launch(void* const* d_in, const int* in_sizes, int n_in,
                              void* d_out, int out_size, void* d_ws, size_t ws_size,
                              hipStream_t stream) {
    const float* query = (const float*)d_in[0];
    const float* key   = (const float*)d_in[1];
    const float* value = (const float*)d_in[2];
    const int*   mask  = (const int*)d_in[3];
    const float* Wq = (const float*)d_in[4];
    const float* bq = (const float*)d_in[5];
    const float* Wk = (const float*)d_in[6];
    const float* bk = (const float*)d_in[7];
    const float* Wv = (const float*)d_in[8];
    const float* bv = (const float*)d_in[9];
    const float* Wo = (const float*)d_in[10];
    const float* bo = (const float*)d_in[11];
    float* out = (float*)d_out;

    char* ws = (char*)d_ws;
    ushort* Wqbf  = (ushort*)(ws + 0);                  // 512 KB
    ushort* Wobf  = (ushort*)(ws + 524288u);            // 512 KB
    ushort* Wkbf  = (ushort*)(ws + 1048576u);           // 512 KB
    ushort* Wvbf  = (ushort*)(ws + 1572864u);           // 512 KB
    ushort* keybf = (ushort*)(ws + 2097152u);           // 128 KB
    ushort* valbf = (ushort*)(ws + 2228224u);           // 128 KB
    float*  kproj = (float*)(ws + 2621440u);            // 256 KB
    float*  vproj = (float*)(ws + 2883584u);            // 256 KB
    ushort* xbf   = (ushort*)(ws + (4u << 20));         // 8 MB (8192 x 512 bf16)

    // fp32->bf16: 4 weights + key/value, one dispatch
    convert_all<<<dim3(256, 5), 256, 0, stream>>>(Wq, Wo, Wk, Wv, key, value,
                                                  Wqbf, Wobf, Wkbf, Wvbf, keybf, valbf);

    // K/V projections via MFMA: 8 blocks
    kvgemm<<<8, 256, 0, stream>>>(keybf, valbf, Wkbf, Wvbf, bk, bv, kproj, vproj);

    // fused q-projection + two-stage attention: 512 blocks x 16 t-rows, wave=head
    qattn<<<512, 512, 0, stream>>>(query, Wqbf, bq, kproj, vproj, mask, xbf);

    // output projection: M = 8192, bf16 A, fp32 out
    gemm_mfma<<<256, 256, 0, stream>>>(xbf, Wobf, bo, out, 64);

    (void)in_sizes; (void)n_in; (void)out_size; (void)ws_size;
}